// Round 6
// baseline (501.381 us; speedup 1.0000x reference)
//
#include <hip/hip_runtime.h>
#include <math.h>

#define L_DIM 8
#define T_DIM 128
#define S_DIM 128
#define SP1   129
#define BIGF  1000000000.0f
#define EPSF  1e-5f
#define NTHREADS 1024
#define NWAVES 16

// ---- DPP cross-lane reductions on the VALU pipe (no DS-pipe traffic) ----
template<int CTRL>
__device__ __forceinline__ float dpp_add_part(float x) {
    int r = __builtin_amdgcn_update_dpp(0, __float_as_int(x), CTRL, 0xF, 0xF, false);
    return __int_as_float(r);
}
template<int CTRL>
__device__ __forceinline__ float dpp_self(float x) {
    int r = __builtin_amdgcn_update_dpp(__float_as_int(x), __float_as_int(x), CTRL, 0xF, 0xF, false);
    return __int_as_float(r);
}
__device__ __forceinline__ float dppSum63(float x) {
    x += dpp_add_part<0x111>(x);  // row_shr:1
    x += dpp_add_part<0x112>(x);  // row_shr:2
    x += dpp_add_part<0x114>(x);  // row_shr:4
    x += dpp_add_part<0x118>(x);  // row_shr:8
    x += dpp_add_part<0x142>(x);  // row_bcast:15
    x += dpp_add_part<0x143>(x);  // row_bcast:31
    return x;                     // total in lane 63
}
__device__ __forceinline__ float dppMax63(float x) {
    x = fmaxf(x, dpp_self<0x111>(x));
    x = fmaxf(x, dpp_self<0x112>(x));
    x = fmaxf(x, dpp_self<0x114>(x));
    x = fmaxf(x, dpp_self<0x118>(x));
    x = fmaxf(x, dpp_self<0x142>(x));
    x = fmaxf(x, dpp_self<0x143>(x));
    return x;                     // max in lane 63
}
__device__ __forceinline__ float lane63(float x) {
    return __int_as_float(__builtin_amdgcn_readlane(__float_as_int(x), 63));
}

// Full 384-row matvec (t-attention qkv), 8 rows/wave per iter; DPP reductions.
__device__ __forceinline__ void qkv_matvec(const float* __restrict__ base,
                                           float vin0, float vin1,
                                           int lane, int wid,
                                           float* __restrict__ lds_q,
                                           float* __restrict__ lds_k,
                                           float* __restrict__ lds_v)
{
#pragma unroll
    for (int it = 0; it < 3; ++it) {
        float* dst = (it == 0) ? lds_q : (it == 1) ? lds_k : lds_v;
        const float* bb = base + (size_t)it * S_DIM * SP1;
        float lo[8], hi[8], bias[8], acc[8];
#pragma unroll
        for (int u = 0; u < 8; ++u) {
            const float* row = bb + (size_t)(wid + u * NWAVES) * SP1;
            lo[u]   = row[lane];
            hi[u]   = row[lane + 64];
            bias[u] = row[128];
        }
#pragma unroll
        for (int u = 0; u < 8; ++u) acc[u] = lo[u] * vin0 + hi[u] * vin1;
#pragma unroll
        for (int u = 0; u < 8; ++u) acc[u] = dppSum63(acc[u]);
        if (lane == 63) {
#pragma unroll
            for (int u = 0; u < 8; ++u) dst[wid + u * NWAVES] = acc[u] + bias[u];
        }
    }
}

// Full 128-row softmax (t-attention), 8 rows/wave.
__device__ __forceinline__ void attn_softmax_full(int lane, int wid,
                                                  const float* __restrict__ lds_q,
                                                  const float* __restrict__ lds_k,
                                                  const float* __restrict__ lds_v,
                                                  const float* __restrict__ resid,
                                                  float* __restrict__ lds_out)
{
    const float scale = 0.08838834764831845f; // rsqrt(128)
    float k0 = lds_k[lane], k1 = lds_k[lane + 64];
    float v0 = lds_v[lane], v1 = lds_v[lane + 64];

    float s1[8], s2[8], mx[8];
#pragma unroll
    for (int u = 0; u < 8; ++u) {
        float q = lds_q[wid + u * NWAVES];
        s1[u] = q * k0 * scale;
        s2[u] = q * k1 * scale;
    }
#pragma unroll
    for (int u = 0; u < 8; ++u) mx[u] = lane63(dppMax63(fmaxf(s1[u], s2[u])));
    float den[8], num[8];
#pragma unroll
    for (int u = 0; u < 8; ++u) {
        float e1 = __expf(s1[u] - mx[u]);
        float e2 = __expf(s2[u] - mx[u]);
        den[u] = e1 + e2;
        num[u] = e1 * v0 + e2 * v1;
    }
#pragma unroll
    for (int u = 0; u < 8; ++u) { den[u] = dppSum63(den[u]); num[u] = dppSum63(num[u]); }
    if (lane == 63) {
#pragma unroll
        for (int u = 0; u < 8; ++u) {
            int r = wid + u * NWAVES;
            lds_out[r] = num[u] / den[u] + resid[r];
        }
    }
}

__global__ __launch_bounds__(NTHREADS)
void net_kernel(const float* __restrict__ x,
                const float* __restrict__ W,
                const float* __restrict__ maskp,
                const float* __restrict__ attn_t,
                const float* __restrict__ attn_n,
                const float* __restrict__ norm_params,
                const float* __restrict__ ada,
                float* __restrict__ out,
                unsigned long long* __restrict__ mbox,   // 7 x 128 tagged vals
                unsigned long long* __restrict__ kvx,    // 128 x 2 x 128 tagged k/v halves
                unsigned long long* __restrict__ paff)   // 128 tagged aff partials (h1->h0)
{
    const int bx   = blockIdx.x;
    const int t    = bx & (T_DIM - 1);
    const int h    = bx >> 7;             // pair half; partner is bx ^ 128 (same XCD under %8)
    const int tid  = threadIdx.x;
    const int lane = tid & 63;
    const int wid  = tid >> 6;

    __shared__ float lds_vals[S_DIM];
    __shared__ float lds_q[S_DIM], lds_k[S_DIM], lds_v[S_DIM];
    __shared__ float lds_tv[S_DIM];
    __shared__ float lds_vn[S_DIM];
    __shared__ float lds_m[S_DIM];
    __shared__ float lds_red[NWAVES];

    const float scale = 0.08838834764831845f; // rsqrt(128)

    for (int b = 0; b < L_DIM; ++b) {
        // ---- P1: prev vals via tagged relaxed mailboxes + mask row ----
        if (tid < S_DIM) {
            float v;
            if (b == 0) {
                v = x[tid];
            } else {
                const unsigned long long* mb = mbox + (size_t)(b - 1) * T_DIM;
                unsigned long long w;
                do {
                    w = __hip_atomic_load(&mb[tid], __ATOMIC_RELAXED, __HIP_MEMORY_SCOPE_AGENT);
                } while ((unsigned int)(w >> 32) != (unsigned int)b);
                float raw = __uint_as_float((unsigned int)w);
                float a0 = ada[((b - 1) * T_DIM + tid) * 2 + 0];
                float a1 = ada[((b - 1) * T_DIM + tid) * 2 + 1];
                float z  = raw * a0;
                float z3 = z * z * z;
                float g  = 0.5f * z * (1.0f + tanhf(0.7978845608028654f * (z + 0.044715f * z3)));
                v = g * a1;
            }
            lds_vals[tid] = v;
            lds_m[tid] = maskp[(b * T_DIM + t) * S_DIM + tid];
        }
        __syncthreads();

        // ---- P2: LayerNorm (redundant per WG) ----
        {
            float v = (tid < S_DIM) ? lds_vals[tid] : 0.0f;
            float s = lane63(dppSum63(v));
            if (lane == 0) lds_red[wid] = s;
            __syncthreads();
            float tot = 0.0f;
            for (int i = 0; i < NWAVES; ++i) tot += lds_red[i];
            float mu = tot * (1.0f / 128.0f);
            __syncthreads();
            float d = (tid < S_DIM) ? (v - mu) : 0.0f;
            float s2 = lane63(dppSum63(d * d));
            if (lane == 0) lds_red[wid] = s2;
            __syncthreads();
            float tot2 = 0.0f;
            for (int i = 0; i < NWAVES; ++i) tot2 += lds_red[i];
            float var = tot2 * (1.0f / 128.0f);
            float rstd = rsqrtf(var + EPSF);
            if (tid < S_DIM) {
                float np0 = norm_params[(b * 2 + 0) * S_DIM + tid];
                float np1 = norm_params[(b * 2 + 1) * S_DIM + tid];
                lds_vals[tid] = (v - mu) * rstd * np0 + np1;
            }
            __syncthreads();
        }

        // ---- P3: t-attention qkv, full (redundant per WG; attn_t L2-resident) ----
        {
            float vin0 = lds_vals[lane], vin1 = lds_vals[lane + 64];
            qkv_matvec(attn_t + (size_t)b * 3 * S_DIM * SP1, vin0, vin1,
                       lane, wid, lds_q, lds_k, lds_v);
        }
        __syncthreads();

        // ---- P4: t-attention softmax, full ----
        attn_softmax_full(lane, wid, lds_q, lds_k, lds_v, lds_vals, lds_tv);
        __syncthreads();

        // ---- P5: n-qkv HALF (this WG's 64 rows of each of q,k,v), one load batch ----
        {
            const float* base = attn_n + (size_t)(b * T_DIM + t) * 3 * S_DIM * SP1;
            float tv0 = lds_tv[lane], tv1 = lds_tv[lane + 64];
            float lo[12], hi[12], bias[12], acc[12];
#pragma unroll
            for (int c = 0; c < 3; ++c) {
#pragma unroll
                for (int u = 0; u < 4; ++u) {
                    int i = c * 4 + u;
                    int r = h * 64 + (wid << 2) + u;
                    const float* row = base + ((size_t)c * S_DIM + r) * SP1;
                    lo[i]   = row[lane];
                    hi[i]   = row[lane + 64];
                    bias[i] = row[128];
                }
            }
#pragma unroll
            for (int i = 0; i < 12; ++i) acc[i] = lo[i] * tv0 + hi[i] * tv1;
#pragma unroll
            for (int i = 0; i < 12; ++i) acc[i] = dppSum63(acc[i]);
            if (lane == 63) {
                unsigned long long* myslots = kvx + ((size_t)t * 2 + h) * 128;
                unsigned long long tag = (unsigned long long)(unsigned int)(b + 1) << 32;
#pragma unroll
                for (int c = 0; c < 3; ++c) {
#pragma unroll
                    for (int u = 0; u < 4; ++u) {
                        int i = c * 4 + u;
                        int j = (wid << 2) + u;          // 0..63 within half
                        int r = h * 64 + j;
                        float val = acc[i] + bias[i];
                        if (c == 0) {
                            lds_q[r] = val;
                        } else if (c == 1) {
                            lds_k[r] = val;
                            __hip_atomic_store(&myslots[j], tag | __float_as_uint(val),
                                               __ATOMIC_RELAXED, __HIP_MEMORY_SCOPE_AGENT);
                        } else {
                            lds_v[r] = val;
                            __hip_atomic_store(&myslots[64 + j], tag | __float_as_uint(val),
                                               __ATOMIC_RELAXED, __HIP_MEMORY_SCOPE_AGENT);
                        }
                    }
                }
            }
        }
        // no __syncthreads needed here: P6 pollers touch disjoint LDS, stores precede polls in-wave

        // ---- P6: poll partner's k/v half (tid<128; tag exact-match) ----
        if (tid < 128) {
            const unsigned long long* slot = kvx + ((size_t)t * 2 + (1 - h)) * 128 + tid;
            unsigned long long w;
            do {
                w = __hip_atomic_load(slot, __ATOMIC_RELAXED, __HIP_MEMORY_SCOPE_AGENT);
            } while ((unsigned int)(w >> 32) != (unsigned int)(b + 1));
            float val = __uint_as_float((unsigned int)w);
            int r = (1 - h) * 64 + (tid & 63);
            if (tid < 64) lds_k[r] = val; else lds_v[r] = val;
        }
        __syncthreads();

        // ---- P7: n-softmax, own 64 rows (4/wave), masked ----
        {
            float k0 = lds_k[lane], k1 = lds_k[lane + 64];
            float v0 = lds_v[lane], v1 = lds_v[lane + 64];
            float m0 = lds_m[lane], m1 = lds_m[lane + 64];
            float s1[4], s2[4], mx[4];
#pragma unroll
            for (int u = 0; u < 4; ++u) {
                int r = h * 64 + (wid << 2) + u;
                float q  = lds_q[r];
                float mr = lds_m[r];
                s1[u] = q * k0 * scale - BIGF * (1.0f - mr * m0);
                s2[u] = q * k1 * scale - BIGF * (1.0f - mr * m1);
            }
#pragma unroll
            for (int u = 0; u < 4; ++u) mx[u] = lane63(dppMax63(fmaxf(s1[u], s2[u])));
            float den[4], num[4];
#pragma unroll
            for (int u = 0; u < 4; ++u) {
                float e1 = __expf(s1[u] - mx[u]);
                float e2 = __expf(s2[u] - mx[u]);
                den[u] = e1 + e2;
                num[u] = e1 * v0 + e2 * v1;
            }
#pragma unroll
            for (int u = 0; u < 4; ++u) { den[u] = dppSum63(den[u]); num[u] = dppSum63(num[u]); }
            if (lane == 63) {
#pragma unroll
                for (int u = 0; u < 4; ++u) {
                    int r = h * 64 + (wid << 2) + u;
                    lds_vn[r] = num[u] / den[u] + lds_tv[r];
                }
            }
        }
        __syncthreads();

        // ---- P8: aff partial over own half; h=1 sends partial, h=0 publishes ----
        if (tid < 64) {
            const float* wrow = W + (size_t)(b * T_DIM + t) * SP1;
            int s = h * 64 + lane;
            float term = wrow[s] * lds_m[s] * lds_vn[s];
            float p = dppSum63(term);     // partial in lane 63 of wave 0
            if (lane == 63) {
                unsigned long long tag = (unsigned long long)(unsigned int)(b + 1) << 32;
                if (h == 1) {
                    __hip_atomic_store(&paff[t], tag | __float_as_uint(p),
                                       __ATOMIC_RELAXED, __HIP_MEMORY_SCOPE_AGENT);
                } else {
                    unsigned long long w;
                    do {
                        w = __hip_atomic_load(&paff[t], __ATOMIC_RELAXED, __HIP_MEMORY_SCOPE_AGENT);
                    } while ((unsigned int)(w >> 32) != (unsigned int)(b + 1));
                    float aff = p + __uint_as_float((unsigned int)w) + wrow[128];
                    if (b == L_DIM - 1) {
                        out[t] = aff;
                    } else {
                        __hip_atomic_store(&mbox[(size_t)b * T_DIM + t],
                                           tag | __float_as_uint(aff),
                                           __ATOMIC_RELAXED, __HIP_MEMORY_SCOPE_AGENT);
                    }
                }
            }
        }
        __syncthreads(); // protect LDS buffers before next block reuses them
    }
}

extern "C" void kernel_launch(void* const* d_in, const int* in_sizes, int n_in,
                              void* d_out, int out_size, void* d_ws, size_t ws_size,
                              hipStream_t stream) {
    const float* x           = (const float*)d_in[0];
    const float* W           = (const float*)d_in[1];
    const float* maskp       = (const float*)d_in[2];
    const float* attn_t      = (const float*)d_in[3];
    const float* attn_n      = (const float*)d_in[4];
    // d_in[5] = attn_mask_n (67 MB) intentionally unused: recomputed from mask
    const float* norm_params = (const float*)d_in[6];
    const float* ada         = (const float*)d_in[7];
    float* out = (float*)d_out;

    // workspace layout (all tagged-u64 arrays; tags never match 0x00.. or 0xAA.. poison)
    unsigned long long* mbox = (unsigned long long*)d_ws;                        // 7*128
    unsigned long long* kvx  = (unsigned long long*)((char*)d_ws + 7168);        // 128*2*128
    unsigned long long* paff = (unsigned long long*)((char*)d_ws + 7168 + 262144); // 128

    hipMemsetAsync(d_ws, 0, 7168 + 262144 + 1024, stream);

    void* args[] = { (void*)&x, (void*)&W, (void*)&maskp, (void*)&attn_t, (void*)&attn_n,
                     (void*)&norm_params, (void*)&ada, (void*)&out,
                     (void*)&mbox, (void*)&kvx, (void*)&paff };
    hipLaunchCooperativeKernel((const void*)net_kernel, dim3(2 * T_DIM), dim3(NTHREADS),
                               args, 0, stream);
}